// Round 6
// baseline (844.804 us; speedup 1.0000x reference)
//
#include <hip/hip_runtime.h>
#include <stdint.h>

#define NB 8
#define NC 64
#define NN 4096
#define NK 16
#define NO 64
#define TILE 64
#define NCHUNK 2
#define CHCOLS (NN / NCHUNK)     // 2048 cols per chunk
#define NTILES (CHCOLS / TILE)   // 32

// ---------------------------------------------------------------------------
// Kernel 1: per-point projections + squared norms. (unchanged, proven)
// PQ[b][n][r], r in [0,192): 0..63 = x·(W1e-W2e)^T + b_edge, 64..127 = x·W2e^T,
// 128..191 = x·W2a^T   (Q1 and b_att cancel in the softmax over k)
// ---------------------------------------------------------------------------
__global__ __launch_bounds__(256) void proj_kernel(
    const float* __restrict__ x, const float* __restrict__ We,
    const float* __restrict__ be, const float* __restrict__ Wa,
    float* __restrict__ PQ, float* __restrict__ sq)
{
  __shared__ float xs[NC][TILE];
  __shared__ float wt[NC][192];
  const int bid = blockIdx.x;
  const int b   = bid >> 6;
  const int n0  = (bid & 63) * TILE;
  const int tid = threadIdx.x;

  const float4* xg4 = (const float4*)x;
  float4* xs4 = (float4*)xs;
  for (int i = tid; i < NC * TILE / 4; i += 256) {
    int c = i >> 4, p4 = i & 15;
    xs4[c * 16 + p4] = xg4[(b * NC + c) * (NN / 4) + (n0 >> 2) + p4];
  }
  for (int i = tid; i < 64 * NC; i += 256) {
    int o = i >> 6, c = i & 63;
    float w1 = We[o * 128 + c], w2 = We[o * 128 + 64 + c];
    wt[c][o]        = w1 - w2;
    wt[c][64 + o]   = w2;
    wt[c][128 + o]  = Wa[o * 128 + 64 + c];
  }
  __syncthreads();

  if (tid >= 192) {
    int p = tid - 192;
    float s = 0.f;
    #pragma unroll
    for (int c = 0; c < NC; ++c) { float v = xs[c][p]; s = fmaf(v, v, s); }
    sq[b * NN + n0 + p] = s;
  } else {
    const int r = tid;
    float wreg[NC];
    #pragma unroll
    for (int c = 0; c < NC; ++c) wreg[c] = wt[c][r];
    const float bias = (r < 64) ? be[r] : 0.f;
    for (int p = 0; p < TILE; p += 4) {
      float a0 = bias, a1 = bias, a2 = bias, a3 = bias;
      #pragma unroll
      for (int c = 0; c < NC; ++c) {
        float4 xv = *(const float4*)&xs[c][p];
        a0 = fmaf(wreg[c], xv.x, a0);
        a1 = fmaf(wreg[c], xv.y, a1);
        a2 = fmaf(wreg[c], xv.z, a2);
        a3 = fmaf(wreg[c], xv.w, a3);
      }
      int base = (b * NN + n0 + p) * 192 + r;
      PQ[base]           = a0;
      PQ[base + 192]     = a1;
      PQ[base + 2 * 192] = a2;
      PQ[base + 3 * 192] = a3;
    }
  }
}

// ---------------------------------------------------------------------------
// Kernel 2: fused pairwise-distance + streaming top-16 over a 2048-col chunk.
// Thread = 1 row x 16 cols. Rows in registers (32 at a time, re-read from
// L1-hot global; opaque-zero asm stops loop-invariant hoisting). Dists stay
// in registers -> no distT, no transpose, 1 barrier/tile. colT double-buffered
// (32 KB LDS total). 1024 blocks = exactly 4 blocks/CU, 16 waves/CU.
// Per c: 16B LDS per lane for 16 FMA (4 distinct addrs, 16-way bcast, 2-way
// bank = free). Selection numerics identical to passing R2/R5.
// ---------------------------------------------------------------------------
__global__ __launch_bounds__(256, 4) void knn_kernel(
    const float* __restrict__ x, const float* __restrict__ sq,
    float* __restrict__ partV, unsigned short* __restrict__ partI)
{
  __shared__ float colT[2][NC][TILE];   // 32 KB, [buf][c][p]

  const int bid = blockIdx.x;
  const int b   = bid >> 7;
  const int rt  = (bid >> 1) & 63;
  const int ch  = bid & 1;
  const int r0  = rt * TILE;
  const int c0  = ch * CHCOLS;
  const int tid = threadIdx.x;
  const int r   = tid >> 2;   // owned row (0..63)
  const int g   = tid & 3;    // col group: cols g*16 .. g*16+15

  const float*  xb  = x + (size_t)b * NC * NN;
  const float*  sqg = sq + (size_t)b * NN;
  const float4* xg4 = (const float4*)xb;

  // ---- prologue: stage colT tile 0 through the cache path ----
  #pragma unroll
  for (int ii = 0; ii < 4; ++ii) {
    int i = ii * 256 + tid;
    int c = i >> 4, p4 = i & 15;
    *(float4*)&colT[0][c][p4 * 4] = xg4[c * (NN / 4) + (c0 >> 2) + p4];
  }
  __syncthreads();

  float bv[NK]; int bi[NK];
  #pragma unroll
  for (int t = 0; t < NK; ++t) { bv[t] = 3.0e38f; bi[t] = 0; }
  float rowGuard = 3.0e38f;

  int zr = 0;   // opaque zero: defeats loop-invariant hoisting of row loads

  for (int t = 0; t < NTILES; ++t) {
    const int cur = t & 1;
    asm volatile("" : "+v"(zr));   // zr "changes" each iteration

    // ---- issue next-tile staging loads early (covered by compute) ----
    float4 st[4];
    const bool doStage = (t + 1 < NTILES);
    if (doStage) {
      const int n1n = c0 + (t + 1) * TILE;
      #pragma unroll
      for (int ii = 0; ii < 4; ++ii) {
        int i = ii * 256 + tid;
        int c = i >> 4, p4 = i & 15;
        st[ii] = xg4[c * (NN / 4) + (n1n >> 2) + p4];
      }
    }

    // ---- dot products: 16 register accumulators, rows in 32-reg halves ----
    float acc[16];
    #pragma unroll
    for (int i = 0; i < 16; ++i) acc[i] = 0.f;

    for (int h = 0; h < 2; ++h) {
      float rw[32];
      #pragma unroll
      for (int c2 = 0; c2 < 32; ++c2)
        rw[c2] = xb[(size_t)(h * 32 + c2) * NN + r0 + r + zr];
      #pragma unroll
      for (int c2 = 0; c2 < 32; ++c2) {
        const float av = rw[c2];
        const int c = h * 32 + c2;
        #pragma unroll
        for (int j4 = 0; j4 < 4; ++j4) {
          const float4 bw = *(const float4*)&colT[cur][c][g * 16 + j4 * 4];
          acc[j4 * 4 + 0] = fmaf(av, bw.x, acc[j4 * 4 + 0]);
          acc[j4 * 4 + 1] = fmaf(av, bw.y, acc[j4 * 4 + 1]);
          acc[j4 * 4 + 2] = fmaf(av, bw.z, acc[j4 * 4 + 2]);
          acc[j4 * 4 + 3] = fmaf(av, bw.w, acc[j4 * 4 + 3]);
        }
      }
    }

    // ---- distances in registers + top-k scan ----
    const int n1 = c0 + t * TILE;
    float d[16];
    #pragma unroll
    for (int j4 = 0; j4 < 4; ++j4) {
      const float4 s4 = *(const float4*)&sqg[n1 + g * 16 + j4 * 4];
      d[j4 * 4 + 0] = fmaf(-2.f, acc[j4 * 4 + 0], s4.x);
      d[j4 * 4 + 1] = fmaf(-2.f, acc[j4 * 4 + 1], s4.y);
      d[j4 * 4 + 2] = fmaf(-2.f, acc[j4 * 4 + 2], s4.z);
      d[j4 * 4 + 3] = fmaf(-2.f, acc[j4 * 4 + 3], s4.w);
    }
    float m = d[0]; int mi = 0;
    #pragma unroll
    for (int i = 1; i < 16; ++i) {
      bool c2 = d[i] < m; m = c2 ? d[i] : m; mi = c2 ? i : mi;
    }
    float guard = fminf(bv[NK - 1], rowGuard);
    for (int rnd = 0; rnd < NK; ++rnd) {
      bool ins = m < guard;
      if (!__any(ins)) break;
      float v  = ins ? m : 3.0e38f;
      int  vmi = ins ? mi : -1;
      if (v < bv[NK - 1]) {
        bv[NK - 1] = v; bi[NK - 1] = n1 + g * 16 + vmi;
        #pragma unroll
        for (int q = NK - 1; q > 0; --q) {
          if (bv[q] < bv[q - 1]) {
            float tv = bv[q]; bv[q] = bv[q - 1]; bv[q - 1] = tv;
            int   ti = bi[q]; bi[q] = bi[q - 1]; bi[q - 1] = ti;
          }
        }
      }
      #pragma unroll
      for (int i = 0; i < 16; ++i) d[i] = (i == vmi) ? 3.0e38f : d[i];
      m = d[0]; mi = 0;
      #pragma unroll
      for (int i = 1; i < 16; ++i) {
        bool c2 = d[i] < m; m = c2 ? d[i] : m; mi = c2 ? i : mi;
      }
      guard = fminf(bv[NK - 1], rowGuard);
    }
    // share the 16th-best across the row's 4 lanes
    float g15 = bv[NK - 1];
    g15 = fminf(g15, __shfl_xor(g15, 1));
    g15 = fminf(g15, __shfl_xor(g15, 2));
    rowGuard = g15;

    // ---- write staged tile into the OTHER buffer (disjoint from reads) ----
    if (doStage) {
      #pragma unroll
      for (int ii = 0; ii < 4; ++ii) {
        int i = ii * 256 + tid;
        int c = i >> 4, p4 = i & 15;
        *(float4*)&colT[cur ^ 1][c][p4 * 4] = st[ii];
      }
    }
    __syncthreads();
  }

  // ---- merge the 4 per-row lists (reuse colT as scratch) ----
  float* mv  = &colT[0][0][0];
  int*   mi2 = (int*)&colT[1][0][0];
  #pragma unroll
  for (int t = 0; t < NK; ++t) {
    mv [(r * 4 + g) * NK + t] = bv[t];
    mi2[(r * 4 + g) * NK + t] = bi[t];
  }
  __syncthreads();
  if (g == 0) {
    for (int s2 = 1; s2 < 4; ++s2) {
      for (int t = 0; t < NK; ++t) {
        float v = mv[(r * 4 + s2) * NK + t];
        if (v >= bv[NK - 1]) break;   // lists sorted ascending
        bv[NK - 1] = v; bi[NK - 1] = mi2[(r * 4 + s2) * NK + t];
        #pragma unroll
        for (int q = NK - 1; q > 0; --q) {
          if (bv[q] < bv[q - 1]) {
            float tv = bv[q]; bv[q] = bv[q - 1]; bv[q - 1] = tv;
            int   ti = bi[q]; bi[q] = bi[q - 1]; bi[q - 1] = ti;
          }
        }
      }
    }
    const int L = (b * NCHUNK + ch) * NN + r0 + r;
    #pragma unroll
    for (int t = 0; t < NK; ++t) {
      partV[L * NK + t] = bv[t];
      partI[L * NK + t] = (unsigned short)bi[t];
    }
  }
}

// ---------------------------------------------------------------------------
// Kernel 2b: merge the two chunk top-16 lists per row. (unchanged)
// ---------------------------------------------------------------------------
__global__ __launch_bounds__(256) void merge_kernel(
    const float* __restrict__ partV, const unsigned short* __restrict__ partI,
    int* __restrict__ nn_idx)
{
  const int row = blockIdx.x * 256 + threadIdx.x;
  if (row >= NB * NN) return;
  const int b = row >> 12, n = row & (NN - 1);
  const int LA = (b * NCHUNK + 0) * NN + n;
  const int LB = (b * NCHUNK + 1) * NN + n;

  float bv[NK]; int bi[NK];
  #pragma unroll
  for (int t = 0; t < NK; ++t) {
    bv[t] = partV[LA * NK + t];
    bi[t] = (int)partI[LA * NK + t];
  }
  for (int t = 0; t < NK; ++t) {
    float v = partV[LB * NK + t];
    if (v >= bv[NK - 1]) break;
    bv[NK - 1] = v; bi[NK - 1] = (int)partI[LB * NK + t];
    #pragma unroll
    for (int q = NK - 1; q > 0; --q) {
      if (bv[q] < bv[q - 1]) {
        float tv = bv[q]; bv[q] = bv[q - 1]; bv[q - 1] = tv;
        int   ti = bi[q]; bi[q] = bi[q - 1]; bi[q - 1] = ti;
      }
    }
  }
  #pragma unroll
  for (int t = 0; t < NK; ++t) nn_idx[row * NK + t] = bi[t];
}

// ---------------------------------------------------------------------------
// Kernel 3: gather neighbors' P2/Q2, softmax over k, weighted sum. (unchanged)
// ---------------------------------------------------------------------------
__global__ __launch_bounds__(256) void out_kernel(
    const float* __restrict__ PQ, const int* __restrict__ nn_idx,
    float* __restrict__ out)
{
  __shared__ float ot[TILE][TILE + 1];
  const int bid = blockIdx.x;
  const int b   = bid >> 6;
  const int n0  = (bid & 63) * TILE;
  const int tid = threadIdx.x;
  const int w = tid >> 6, o = tid & 63;

  for (int pi = 0; pi < 16; ++pi) {
    const int p = w * 16 + pi;
    const int n = n0 + p;
    const float* pqn = PQ + (b * NN + n) * 192;
    const float p1b  = pqn[o];
    const int* idxp  = nn_idx + (b * NN + n) * NK;
    float p2[NK], q2[NK];
    #pragma unroll
    for (int t = 0; t < NK; ++t) {
      int j = idxp[t];
      const float* pqj = PQ + (b * NN + j) * 192;
      p2[t] = pqj[64 + o];
      q2[t] = pqj[128 + o];
    }
    float m = q2[0];
    #pragma unroll
    for (int t = 1; t < NK; ++t) m = fmaxf(m, q2[t]);
    float s = 0.f, num = 0.f;
    #pragma unroll
    for (int t = 0; t < NK; ++t) {
      float e = __expf(q2[t] - m);
      s += e;
      num = fmaf(e, p1b + p2[t], num);
    }
    ot[p][o] = num / s;
  }
  __syncthreads();

  const int oo = tid >> 2, qq = tid & 3;
  float* og = out + (b * NO + oo) * NN + n0 + qq * 16;
  #pragma unroll
  for (int i = 0; i < 4; ++i) {
    float4 v;
    v.x = ot[qq * 16 + i * 4 + 0][oo];
    v.y = ot[qq * 16 + i * 4 + 1][oo];
    v.z = ot[qq * 16 + i * 4 + 2][oo];
    v.w = ot[qq * 16 + i * 4 + 3][oo];
    *(float4*)&og[i * 4] = v;
  }
}

// ---------------------------------------------------------------------------
extern "C" void kernel_launch(void* const* d_in, const int* in_sizes, int n_in,
                              void* d_out, int out_size, void* d_ws, size_t ws_size,
                              hipStream_t stream)
{
  const float* x  = (const float*)d_in[0];
  const float* We = (const float*)d_in[1];
  const float* be = (const float*)d_in[2];
  const float* Wa = (const float*)d_in[3];
  float* out = (float*)d_out;

  char* ws = (char*)d_ws;
  size_t off = 0;
  float* sq = (float*)(ws + off);  off += (size_t)NB * NN * 4;
  float* PQ = (float*)(ws + off);  off += (size_t)NB * NN * 192 * 4;
  int*   nn = (int*)(ws + off);    off += (size_t)NB * NN * NK * 4;
  float* pV = (float*)(ws + off);  off += (size_t)NB * NCHUNK * NN * NK * 4;
  unsigned short* pI = (unsigned short*)(ws + off);

  dim3 blk(256);
  proj_kernel<<<dim3(NB * (NN / TILE)), blk, 0, stream>>>(x, We, be, Wa, PQ, sq);
  knn_kernel<<<dim3(NB * (NN / TILE) * NCHUNK), blk, 0, stream>>>(x, sq, pV, pI);
  merge_kernel<<<dim3(NB * NN / 256), blk, 0, stream>>>(pV, pI, nn);
  out_kernel<<<dim3(NB * (NN / TILE)), blk, 0, stream>>>(PQ, nn, out);
}

// Round 7
// 526.402 us; speedup vs baseline: 1.6049x; 1.6049x over previous
//
#include <hip/hip_runtime.h>
#include <stdint.h>

#define NB 8
#define NC 64
#define NN 4096
#define NK 16
#define NO 64
#define TILE 64
#define BR 128                   // rows per block
#define NCHUNK 2
#define CHCOLS (NN / NCHUNK)     // 2048 cols per chunk
#define NTILES (CHCOLS / TILE)   // 32

// ---------------------------------------------------------------------------
// Kernel 1: per-point projections + squared norms. (unchanged, proven)
// PQ[b][n][r], r in [0,192): 0..63 = x·(W1e-W2e)^T + b_edge, 64..127 = x·W2e^T,
// 128..191 = x·W2a^T   (Q1 and b_att cancel in the softmax over k)
// ---------------------------------------------------------------------------
__global__ __launch_bounds__(256) void proj_kernel(
    const float* __restrict__ x, const float* __restrict__ We,
    const float* __restrict__ be, const float* __restrict__ Wa,
    float* __restrict__ PQ, float* __restrict__ sq)
{
  __shared__ float xs[NC][TILE];
  __shared__ float wt[NC][192];
  const int bid = blockIdx.x;
  const int b   = bid >> 6;
  const int n0  = (bid & 63) * TILE;
  const int tid = threadIdx.x;

  const float4* xg4 = (const float4*)x;
  float4* xs4 = (float4*)xs;
  for (int i = tid; i < NC * TILE / 4; i += 256) {
    int c = i >> 4, p4 = i & 15;
    xs4[c * 16 + p4] = xg4[(b * NC + c) * (NN / 4) + (n0 >> 2) + p4];
  }
  for (int i = tid; i < 64 * NC; i += 256) {
    int o = i >> 6, c = i & 63;
    float w1 = We[o * 128 + c], w2 = We[o * 128 + 64 + c];
    wt[c][o]        = w1 - w2;
    wt[c][64 + o]   = w2;
    wt[c][128 + o]  = Wa[o * 128 + 64 + c];
  }
  __syncthreads();

  if (tid >= 192) {
    int p = tid - 192;
    float s = 0.f;
    #pragma unroll
    for (int c = 0; c < NC; ++c) { float v = xs[c][p]; s = fmaf(v, v, s); }
    sq[b * NN + n0 + p] = s;
  } else {
    const int r = tid;
    float wreg[NC];
    #pragma unroll
    for (int c = 0; c < NC; ++c) wreg[c] = wt[c][r];
    const float bias = (r < 64) ? be[r] : 0.f;
    for (int p = 0; p < TILE; p += 4) {
      float a0 = bias, a1 = bias, a2 = bias, a3 = bias;
      #pragma unroll
      for (int c = 0; c < NC; ++c) {
        float4 xv = *(const float4*)&xs[c][p];
        a0 = fmaf(wreg[c], xv.x, a0);
        a1 = fmaf(wreg[c], xv.y, a1);
        a2 = fmaf(wreg[c], xv.z, a2);
        a3 = fmaf(wreg[c], xv.w, a3);
      }
      int base = (b * NN + n0 + p) * 192 + r;
      PQ[base]           = a0;
      PQ[base + 192]     = a1;
      PQ[base + 2 * 192] = a2;
      PQ[base + 3 * 192] = a3;
    }
  }
}

// ---------------------------------------------------------------------------
// Kernel 2: fused pairwise-distance + streaming top-16, 128-row x 2048-col
// chunk per block. 512 threads, 4x4 thread tiles. Two-segment phases (R5):
//   A (reads):  issue stage loads(t+1)->regs; scan distT(t-1); compute acc(t)
//   barrier
//   B (writes): distT <- dist(t) (granule-rotated); colT <- staged (t+1)
//   barrier
// LDS = rowT 32K + colT 16K + distT 32K = 81920 B exactly -> 2 blocks/CU
// (LDS-pinned; grid 512 = exactly 2/CU, zero tail, 16 waves/CU).
// Selection numerics bit-identical to passing R2/R5.
// ---------------------------------------------------------------------------
__global__ __launch_bounds__(512, 4) void knn_kernel(
    const float* __restrict__ x, const float* __restrict__ sq,
    float* __restrict__ partV, unsigned short* __restrict__ partI)
{
  __shared__ float rowT[NC][BR];       // 32 KB [c][r]
  __shared__ float colT[NC][TILE];     // 16 KB [c][p]
  __shared__ float distT[BR][TILE];    // 32 KB, granule-rotated rows

  const int bid = blockIdx.x;
  const int b   = bid >> 6;            // 8 batches
  const int rt  = (bid >> 1) & 31;     // 32 row-tiles of 128
  const int ch  = bid & 1;             // 2 col chunks
  const int r0  = rt * BR;
  const int c0  = ch * CHCOLS;
  const int tid = threadIdx.x;

  const int rr   = (tid >> 4) << 2;    // compute: 4 rows (0..124)
  const int cc   = (tid & 15) << 2;    // compute: 4 cols
  const int glw  = tid & 15;           // writer granule (= cc>>2)
  const int srow = tid >> 2;           // scan: row (0..127)
  const int ssub = tid & 3;            // scan: col group (16 cols)

  const float*  xb  = x + (size_t)b * NC * NN;
  const float*  sqg = sq + (size_t)b * NN;
  const float4* xg4 = (const float4*)xb;

  // ---- prologue: stage rowT (128 rows) and colT(tile 0) ----
  {
    float4* rT4 = (float4*)rowT;
    #pragma unroll
    for (int ii = 0; ii < 4; ++ii) {
      int i = ii * 512 + tid;          // 2048 float4s
      int c = i >> 5, p4 = i & 31;
      rT4[c * 32 + p4] = xg4[c * (NN / 4) + (r0 >> 2) + p4];
    }
    float4* cT4 = (float4*)colT;
    #pragma unroll
    for (int ii = 0; ii < 2; ++ii) {
      int i = ii * 512 + tid;          // 1024 float4s
      int c = i >> 4, p4 = i & 15;
      cT4[c * 16 + p4] = xg4[c * (NN / 4) + (c0 >> 2) + p4];
    }
  }
  __syncthreads();

  float bv[NK]; int bi[NK];
  #pragma unroll
  for (int t = 0; t < NK; ++t) { bv[t] = 3.0e38f; bi[t] = 0; }
  float rowGuard = 3.0e38f;

  for (int t = 0; t <= NTILES; ++t) {
    // ================= segment A: reads only =================
    float4 st[2];
    const bool doStage = (t + 1 < NTILES);
    if (doStage) {
      const int n1n = c0 + (t + 1) * TILE;
      #pragma unroll
      for (int ii = 0; ii < 2; ++ii) {
        int i = ii * 512 + tid;
        int c = i >> 4, p4 = i & 15;
        st[ii] = xg4[c * (NN / 4) + (n1n >> 2) + p4];
      }
    }
    float4 sq4;
    if (t < NTILES) sq4 = *(const float4*)&sqg[c0 + t * TILE + cc];

    // ---- scan distT (results of tile t-1) ----
    if (t > 0) {
      const int n1 = c0 + (t - 1) * TILE;
      float d[16];
      #pragma unroll
      for (int j4 = 0; j4 < 4; ++j4) {
        int phys = (ssub * 4 + j4 + srow) & 15;
        float4 t4 = *(const float4*)&distT[srow][phys << 2];
        d[j4 * 4 + 0] = t4.x; d[j4 * 4 + 1] = t4.y;
        d[j4 * 4 + 2] = t4.z; d[j4 * 4 + 3] = t4.w;
      }
      float m = d[0]; int mi = 0;
      #pragma unroll
      for (int i = 1; i < 16; ++i) {
        bool c2 = d[i] < m; m = c2 ? d[i] : m; mi = c2 ? i : mi;
      }
      float guard = fminf(bv[NK - 1], rowGuard);
      for (int rnd = 0; rnd < NK; ++rnd) {
        bool ins = m < guard;
        if (!__any(ins)) break;
        float v  = ins ? m : 3.0e38f;
        int  vmi = ins ? mi : -1;
        if (v < bv[NK - 1]) {
          bv[NK - 1] = v; bi[NK - 1] = n1 + ssub * 16 + vmi;
          #pragma unroll
          for (int q = NK - 1; q > 0; --q) {
            if (bv[q] < bv[q - 1]) {
              float tv = bv[q]; bv[q] = bv[q - 1]; bv[q - 1] = tv;
              int   ti = bi[q]; bi[q] = bi[q - 1]; bi[q - 1] = ti;
            }
          }
        }
        #pragma unroll
        for (int i = 0; i < 16; ++i) d[i] = (i == vmi) ? 3.0e38f : d[i];
        m = d[0]; mi = 0;
        #pragma unroll
        for (int i = 1; i < 16; ++i) {
          bool c2 = d[i] < m; m = c2 ? d[i] : m; mi = c2 ? i : mi;
        }
        guard = fminf(bv[NK - 1], rowGuard);
      }
      // share the 16th-best across the row's 4 lanes
      float g15 = bv[NK - 1];
      g15 = fminf(g15, __shfl_xor(g15, 1));
      g15 = fminf(g15, __shfl_xor(g15, 2));
      rowGuard = g15;
    }

    if (t < NTILES) {
      // ---- compute 4x4 dot tile (identical fmaf order to R2) ----
      float acc[4][4];
      #pragma unroll
      for (int i2 = 0; i2 < 4; ++i2)
        #pragma unroll
        for (int j = 0; j < 4; ++j) acc[i2][j] = 0.f;

      #pragma unroll 8
      for (int c = 0; c < NC; ++c) {
        const float4 av = *(const float4*)&rowT[c][rr];
        const float4 bw = *(const float4*)&colT[c][cc];
        acc[0][0]=fmaf(av.x,bw.x,acc[0][0]); acc[0][1]=fmaf(av.x,bw.y,acc[0][1]);
        acc[0][2]=fmaf(av.x,bw.z,acc[0][2]); acc[0][3]=fmaf(av.x,bw.w,acc[0][3]);
        acc[1][0]=fmaf(av.y,bw.x,acc[1][0]); acc[1][1]=fmaf(av.y,bw.y,acc[1][1]);
        acc[1][2]=fmaf(av.y,bw.z,acc[1][2]); acc[1][3]=fmaf(av.y,bw.w,acc[1][3]);
        acc[2][0]=fmaf(av.z,bw.x,acc[2][0]); acc[2][1]=fmaf(av.z,bw.y,acc[2][1]);
        acc[2][2]=fmaf(av.z,bw.z,acc[2][2]); acc[2][3]=fmaf(av.z,bw.w,acc[2][3]);
        acc[3][0]=fmaf(av.w,bw.x,acc[3][0]); acc[3][1]=fmaf(av.w,bw.y,acc[3][1]);
        acc[3][2]=fmaf(av.w,bw.z,acc[3][2]); acc[3][3]=fmaf(av.w,bw.w,acc[3][3]);
      }

      __syncthreads();   // barrier 1: all reads of distT/colT complete

      // ================= segment B: writes only =================
      #pragma unroll
      for (int i2 = 0; i2 < 4; ++i2) {
        const int row  = rr + i2;
        const int phys = (glw + row) & 15;
        float4 w;
        w.x = fmaf(-2.f, acc[i2][0], sq4.x);
        w.y = fmaf(-2.f, acc[i2][1], sq4.y);
        w.z = fmaf(-2.f, acc[i2][2], sq4.z);
        w.w = fmaf(-2.f, acc[i2][3], sq4.w);
        *(float4*)&distT[row][phys << 2] = w;
      }
      if (doStage) {
        float4* cT4 = (float4*)colT;
        #pragma unroll
        for (int ii = 0; ii < 2; ++ii) {
          int i = ii * 512 + tid;
          int c = i >> 4, p4 = i & 15;
          cT4[c * 16 + p4] = st[ii];
        }
      }
      __syncthreads();   // barrier 2: writes visible to next phase
    }
  }

  // ---- merge the 4 per-row lists (reuse rowT + distT as scratch) ----
  float* mv  = &rowT[0][0];            // 512 lists * 16 * 4B = 32 KB
  int*   mi2 = (int*)&distT[0][0];     // 32 KB
  #pragma unroll
  for (int t = 0; t < NK; ++t) {
    mv [(srow * 4 + ssub) * NK + t] = bv[t];
    mi2[(srow * 4 + ssub) * NK + t] = bi[t];
  }
  __syncthreads();
  if (ssub == 0) {
    for (int s2 = 1; s2 < 4; ++s2) {
      for (int t = 0; t < NK; ++t) {
        float v = mv[(srow * 4 + s2) * NK + t];
        if (v >= bv[NK - 1]) break;   // lists sorted ascending
        bv[NK - 1] = v; bi[NK - 1] = mi2[(srow * 4 + s2) * NK + t];
        #pragma unroll
        for (int q = NK - 1; q > 0; --q) {
          if (bv[q] < bv[q - 1]) {
            float tv = bv[q]; bv[q] = bv[q - 1]; bv[q - 1] = tv;
            int   ti = bi[q]; bi[q] = bi[q - 1]; bi[q - 1] = ti;
          }
        }
      }
    }
    const int L = (b * NCHUNK + ch) * NN + r0 + srow;
    #pragma unroll
    for (int t = 0; t < NK; ++t) {
      partV[L * NK + t] = bv[t];
      partI[L * NK + t] = (unsigned short)bi[t];
    }
  }
}

// ---------------------------------------------------------------------------
// Kernel 2b: merge the two chunk top-16 lists per row. (unchanged)
// ---------------------------------------------------------------------------
__global__ __launch_bounds__(256) void merge_kernel(
    const float* __restrict__ partV, const unsigned short* __restrict__ partI,
    int* __restrict__ nn_idx)
{
  const int row = blockIdx.x * 256 + threadIdx.x;
  if (row >= NB * NN) return;
  const int b = row >> 12, n = row & (NN - 1);
  const int LA = (b * NCHUNK + 0) * NN + n;
  const int LB = (b * NCHUNK + 1) * NN + n;

  float bv[NK]; int bi[NK];
  #pragma unroll
  for (int t = 0; t < NK; ++t) {
    bv[t] = partV[LA * NK + t];
    bi[t] = (int)partI[LA * NK + t];
  }
  for (int t = 0; t < NK; ++t) {
    float v = partV[LB * NK + t];
    if (v >= bv[NK - 1]) break;
    bv[NK - 1] = v; bi[NK - 1] = (int)partI[LB * NK + t];
    #pragma unroll
    for (int q = NK - 1; q > 0; --q) {
      if (bv[q] < bv[q - 1]) {
        float tv = bv[q]; bv[q] = bv[q - 1]; bv[q - 1] = tv;
        int   ti = bi[q]; bi[q] = bi[q - 1]; bi[q - 1] = ti;
      }
    }
  }
  #pragma unroll
  for (int t = 0; t < NK; ++t) nn_idx[row * NK + t] = bi[t];
}

// ---------------------------------------------------------------------------
// Kernel 3: gather neighbors' P2/Q2, softmax over k, weighted sum. (unchanged)
// ---------------------------------------------------------------------------
__global__ __launch_bounds__(256) void out_kernel(
    const float* __restrict__ PQ, const int* __restrict__ nn_idx,
    float* __restrict__ out)
{
  __shared__ float ot[TILE][TILE + 1];
  const int bid = blockIdx.x;
  const int b   = bid >> 6;
  const int n0  = (bid & 63) * TILE;
  const int tid = threadIdx.x;
  const int w = tid >> 6, o = tid & 63;

  for (int pi = 0; pi < 16; ++pi) {
    const int p = w * 16 + pi;
    const int n = n0 + p;
    const float* pqn = PQ + (b * NN + n) * 192;
    const float p1b  = pqn[o];
    const int* idxp  = nn_idx + (b * NN + n) * NK;
    float p2[NK], q2[NK];
    #pragma unroll
    for (int t = 0; t < NK; ++t) {
      int j = idxp[t];
      const float* pqj = PQ + (b * NN + j) * 192;
      p2[t] = pqj[64 + o];
      q2[t] = pqj[128 + o];
    }
    float m = q2[0];
    #pragma unroll
    for (int t = 1; t < NK; ++t) m = fmaxf(m, q2[t]);
    float s = 0.f, num = 0.f;
    #pragma unroll
    for (int t = 0; t < NK; ++t) {
      float e = __expf(q2[t] - m);
      s += e;
      num = fmaf(e, p1b + p2[t], num);
    }
    ot[p][o] = num / s;
  }
  __syncthreads();

  const int oo = tid >> 2, qq = tid & 3;
  float* og = out + (b * NO + oo) * NN + n0 + qq * 16;
  #pragma unroll
  for (int i = 0; i < 4; ++i) {
    float4 v;
    v.x = ot[qq * 16 + i * 4 + 0][oo];
    v.y = ot[qq * 16 + i * 4 + 1][oo];
    v.z = ot[qq * 16 + i * 4 + 2][oo];
    v.w = ot[qq * 16 + i * 4 + 3][oo];
    *(float4*)&og[i * 4] = v;
  }
}

// ---------------------------------------------------------------------------
extern "C" void kernel_launch(void* const* d_in, const int* in_sizes, int n_in,
                              void* d_out, int out_size, void* d_ws, size_t ws_size,
                              hipStream_t stream)
{
  const float* x  = (const float*)d_in[0];
  const float* We = (const float*)d_in[1];
  const float* be = (const float*)d_in[2];
  const float* Wa = (const float*)d_in[3];
  float* out = (float*)d_out;

  char* ws = (char*)d_ws;
  size_t off = 0;
  float* sq = (float*)(ws + off);  off += (size_t)NB * NN * 4;
  float* PQ = (float*)(ws + off);  off += (size_t)NB * NN * 192 * 4;
  int*   nn = (int*)(ws + off);    off += (size_t)NB * NN * NK * 4;
  float* pV = (float*)(ws + off);  off += (size_t)NB * NCHUNK * NN * NK * 4;
  unsigned short* pI = (unsigned short*)(ws + off);

  dim3 blk(256);
  proj_kernel<<<dim3(NB * (NN / TILE)), blk, 0, stream>>>(x, We, be, Wa, PQ, sq);
  knn_kernel<<<dim3(NB * (NN / BR) * NCHUNK), dim3(512), 0, stream>>>(x, sq, pV, pI);
  merge_kernel<<<dim3(NB * NN / 256), blk, 0, stream>>>(pV, pI, nn);
  out_kernel<<<dim3(NB * (NN / TILE)), blk, 0, stream>>>(PQ, nn, out);
}